// Round 6
// baseline (673.888 us; speedup 1.0000x reference)
//
#include <hip/hip_runtime.h>
#include <math.h>

#define S_DIM 1024
#define B_DIM 4
#define E_DIM 1024
#define H_DIM 16
#define M_DIM 128
#define V_DIM 64

typedef __attribute__((ext_vector_type(8))) short short8;
typedef __attribute__((ext_vector_type(4))) float f32x4;
typedef __attribute__((ext_vector_type(4))) int int4v;

__device__ __forceinline__ unsigned short f2bf(float f) {
    union { float f; unsigned u; } v; v.f = f;
    unsigned r = v.u + 0x7FFFu + ((v.u >> 16) & 1u);   // round-to-nearest-even
    return (unsigned short)(r >> 16);
}

__device__ __forceinline__ void async16(const unsigned short* g, unsigned short* l) {
    __builtin_amdgcn_global_load_lds(
        (const __attribute__((address_space(1))) void*)g,
        (__attribute__((address_space(3))) void*)l,
        16, 0, 0);
}

// ---------------- convert: fp32 (re,im) -> bf16, all 4 tensors in one launch ----------------
// segments (in float4 units): x 1048576 | wq 524288 | wk 524288 | wv 262144
__global__ __launch_bounds__(256) void convert_all(
    const float* __restrict__ xre,  const float* __restrict__ xim,
    const float* __restrict__ wqre, const float* __restrict__ wqim,
    const float* __restrict__ wkre, const float* __restrict__ wkim,
    const float* __restrict__ wvre, const float* __restrict__ wvim,
    unsigned short* __restrict__ xbre, unsigned short* __restrict__ xbim,
    unsigned short* __restrict__ wbre, unsigned short* __restrict__ wbim)
{
    const int i = blockIdx.x * 256 + threadIdx.x;
    const float *re, *im;
    unsigned short *dr, *di;
    int j;
    if (i < 1048576)      { re = xre;  im = xim;  dr = xbre;               di = xbim;               j = i; }
    else if (i < 1572864) { re = wqre; im = wqim; dr = wbre;               di = wbim;               j = i - 1048576; }
    else if (i < 2097152) { re = wkre; im = wkim; dr = wbre + 2048 * 1024; di = wbim + 2048 * 1024; j = i - 1572864; }
    else                  { re = wvre; im = wvim; dr = wbre + 4096 * 1024; di = wbim + 4096 * 1024; j = i - 2097152; }
    float4 r = ((const float4*)re)[j];
    float4 m = ((const float4*)im)[j];
    ushort4 ro, mo;
    ro.x = f2bf(r.x); ro.y = f2bf(r.y); ro.z = f2bf(r.z); ro.w = f2bf(r.w);
    mo.x = f2bf(m.x); mo.y = f2bf(m.y); mo.z = f2bf(m.z); mo.w = f2bf(m.w);
    ((ushort4*)dr)[j] = ro;
    ((ushort4*)di)[j] = mo;
}

// wo (e,f) -> woT (f,e) bf16
__global__ __launch_bounds__(256) void transpose_wo(
    const float* __restrict__ wore, const float* __restrict__ woim,
    unsigned short* __restrict__ wtre, unsigned short* __restrict__ wtim)
{
    __shared__ float tr[32][33], ti[32][33];
    const int bx = blockIdx.x * 32;   // e range
    const int by = blockIdx.y * 32;   // f range
    const int tx = threadIdx.x & 31, ty = threadIdx.x >> 5;
    for (int i = ty; i < 32; i += 8) {
        tr[i][tx] = wore[(bx + i) * E_DIM + by + tx];
        ti[i][tx] = woim[(bx + i) * E_DIM + by + tx];
    }
    __syncthreads();
    for (int i = ty; i < 32; i += 8) {
        wtre[(by + i) * E_DIM + bx + tx] = f2bf(tr[tx][i]);
        wtim[(by + i) * E_DIM + bx + tx] = f2bf(ti[tx][i]);
    }
}

// v planes [bh][t][64] -> v^T planes [bh][v][1024]
__global__ __launch_bounds__(256) void vtrans(
    const unsigned short* __restrict__ vrp, const unsigned short* __restrict__ vip,
    unsigned short* __restrict__ vrt, unsigned short* __restrict__ vit)
{
    __shared__ unsigned short tl[2][64][66];
    const int tid = threadIdx.x;
    const int t0 = blockIdx.x * 64;
    const int bh = blockIdx.y;
    #pragma unroll
    for (int pl = 0; pl < 2; ++pl) {
        const unsigned short* src = pl ? vip : vrp;
        #pragma unroll
        for (int p = 0; p < 2; ++p) {
            const int row = p * 32 + (tid >> 3);
            const int col = (tid & 7) * 8;
            short8 d = *(const short8*)&src[((size_t)bh * S_DIM + t0 + row) * V_DIM + col];
            #pragma unroll
            for (int j = 0; j < 8; ++j) tl[pl][row][col + j] = (unsigned short)d[j];
        }
    }
    __syncthreads();
    #pragma unroll
    for (int pl = 0; pl < 2; ++pl) {
        unsigned short* dst = pl ? vit : vrt;
        #pragma unroll
        for (int p = 0; p < 2; ++p) {
            const int v = p * 32 + (tid >> 3);
            const int tc = (tid & 7) * 8;
            short8 d;
            #pragma unroll
            for (int j = 0; j < 8; ++j) d[j] = (short)tl[pl][tc + j][v];
            *(short8*)&dst[((size_t)bh * V_DIM + v) * S_DIM + t0 + tc] = d;
        }
    }
}

// ---------------- complex bf16 MFMA GEMM: C = A * B^T ----------------
// Frozen at round-5 state (154 us, MfmaUtil 51%, 0 bank conflicts):
// block 128x128, 4 waves (2x2), wave tile 64x64, 16x16x32 frags, BK=32,
// T3-min double-buffer, chunk-XOR swizzle. Only change this round: the
// attention scale 1/sqrt(128) is folded into the q-plane epilogue (the q
// outputs feed only attention, which now skips the per-element scale).
// MODE 0: Mr=4096 (s,b), Nc=5120 (q|k|v) -> bf16 planes qr/qi/kr/ki/vr/vi
// MODE 1: Mr=4096, Nc=1024 -> out = acc + x (fp32, stacked re/im), plain stores
template<int MODE>
__global__ __launch_bounds__(256, 2) void cgemm(
    const unsigned short* __restrict__ Are, const unsigned short* __restrict__ Aim,
    const unsigned short* __restrict__ Bre, const unsigned short* __restrict__ Bim,
    unsigned short* __restrict__ qrp, unsigned short* __restrict__ qip,
    unsigned short* __restrict__ krp, unsigned short* __restrict__ kip,
    unsigned short* __restrict__ vrp, unsigned short* __restrict__ vip,
    const float* __restrict__ xre, const float* __restrict__ xim,
    float* __restrict__ out)
{
    // 64 KB: 2 slice buffers x (Ar[128][32] | Ai[128][32] | Br[128][32] | Bi[128][32])
    __shared__ __align__(16) unsigned short lds[32768];
    const int tid  = threadIdx.x;
    const int wave = tid >> 6;
    const int lane = tid & 63;
    const int r0 = blockIdx.x * 128;
    const int j0 = blockIdx.y * 128;
    const int wm = (wave >> 1) * 64;   // m half
    const int wn = (wave & 1) * 64;    // n half

    f32x4 accre[4][4], accim[4][4];
    #pragma unroll
    for (int i = 0; i < 4; ++i)
        #pragma unroll
        for (int j = 0; j < 4; ++j) {
            accre[i][j] = (f32x4){0.f, 0.f, 0.f, 0.f};
            accim[i][j] = (f32x4){0.f, 0.f, 0.f, 0.f};
        }

    const int sr   = tid >> 2;
    const int sc   = (tid & 3) * 8;                          // physical chunk (shorts)
    const int scol = ((tid & 3) ^ ((tid >> 3) & 3)) * 8;     // pre-swizzled source col

    const int fr = lane & 15;                                // frag m/n index
    const int xc = ((lane >> 4) ^ ((lane >> 1) & 3)) * 8;    // swizzled k-chunk on read

    #define STAGE(sl, bb) { \
        const int kg = (sl) * 32; \
        unsigned short* b_ = &lds[(bb) * 16384]; \
        const size_t ga0 = (size_t)(r0 + sr) * E_DIM + kg + scol; \
        const size_t ga1 = (size_t)(r0 + 64 + sr) * E_DIM + kg + scol; \
        const size_t gb0 = (size_t)(j0 + sr) * E_DIM + kg + scol; \
        const size_t gb1 = (size_t)(j0 + 64 + sr) * E_DIM + kg + scol; \
        async16(Are + ga0, b_ + sr * 32 + sc); \
        async16(Are + ga1, b_ + (64 + sr) * 32 + sc); \
        async16(Aim + ga0, b_ + 4096 + sr * 32 + sc); \
        async16(Aim + ga1, b_ + 4096 + (64 + sr) * 32 + sc); \
        async16(Bre + gb0, b_ + 8192 + sr * 32 + sc); \
        async16(Bre + gb1, b_ + 8192 + (64 + sr) * 32 + sc); \
        async16(Bim + gb0, b_ + 12288 + sr * 32 + sc); \
        async16(Bim + gb1, b_ + 12288 + (64 + sr) * 32 + sc); }

    STAGE(0, 0)
    asm volatile("s_waitcnt vmcnt(0)" ::: "memory");
    __builtin_amdgcn_s_barrier();

    #pragma unroll 1
    for (int s = 0; s < 32; ++s) {
        if (s < 31) STAGE(s + 1, (s + 1) & 1)

        const unsigned short* buf = &lds[(s & 1) * 16384];
        short8 ar[4], ai[4];
        #pragma unroll
        for (int im = 0; im < 4; ++im) {
            const int ro = (wm + im * 16 + fr) * 32 + xc;
            ar[im] = *(const short8*)&buf[ro];
            ai[im] = *(const short8*)&buf[4096 + ro];
        }
        #pragma unroll
        for (int jn = 0; jn < 4; ++jn) {
            const int ro = (wn + jn * 16 + fr) * 32 + xc;
            const short8 br = *(const short8*)&buf[8192 + ro];
            const short8 bi = *(const short8*)&buf[12288 + ro];
            int4v t = *(int4v*)&bi;
            t = t ^ (int)0x80008000;       // bin = -bi (transient)
            const short8 bin = *(short8*)&t;
            #pragma unroll
            for (int im = 0; im < 4; ++im) {
                accre[im][jn] = __builtin_amdgcn_mfma_f32_16x16x32_bf16(ar[im], br,  accre[im][jn], 0, 0, 0);
                accre[im][jn] = __builtin_amdgcn_mfma_f32_16x16x32_bf16(ai[im], bin, accre[im][jn], 0, 0, 0);
                accim[im][jn] = __builtin_amdgcn_mfma_f32_16x16x32_bf16(ar[im], bi,  accim[im][jn], 0, 0, 0);
                accim[im][jn] = __builtin_amdgcn_mfma_f32_16x16x32_bf16(ai[im], br,  accim[im][jn], 0, 0, 0);
            }
        }

        if (s < 31) {
            asm volatile("s_waitcnt vmcnt(0)" ::: "memory");
            __builtin_amdgcn_s_barrier();
        }
    }
    #undef STAGE

    // epilogue: D row = (lane>>4)*4+reg, col = lane&15  [measured m89/m91]
    const float qscale = 0.088388347648318447f;  // 1/sqrt(128), folded into q planes
    #pragma unroll
    for (int im = 0; im < 4; ++im) {
        #pragma unroll
        for (int reg = 0; reg < 4; ++reg) {
            const int r = r0 + wm + im * 16 + (lane >> 4) * 4 + reg;
            #pragma unroll
            for (int jn = 0; jn < 4; ++jn) {
                const int j = j0 + wn + jn * 16 + fr;
                const float vr = accre[im][jn][reg];
                const float vi = accim[im][jn][reg];
                if (MODE == 0) {
                    const int s = r >> 2, b = r & 3;   // r = s*B + b
                    if (j < 2048) {
                        const int h = j >> 7, m = j & 127;
                        const size_t off = ((size_t)(b * H_DIM + h) * S_DIM + s) * M_DIM + m;
                        qrp[off] = f2bf(vr * qscale); qip[off] = f2bf(vi * qscale);
                    } else if (j < 4096) {
                        const int jl = j - 2048, h = jl >> 7, m = jl & 127;
                        const size_t off = ((size_t)(b * H_DIM + h) * S_DIM + s) * M_DIM + m;
                        krp[off] = f2bf(vr); kip[off] = f2bf(vi);
                    } else {
                        const int jl = j - 4096, h = jl >> 6, vv = jl & 63;
                        const size_t off = ((size_t)(b * H_DIM + h) * S_DIM + s) * V_DIM + vv;
                        vrp[off] = f2bf(vr); vip[off] = f2bf(vi);
                    }
                } else {
                    const int idx = r * E_DIM + j;
                    out[idx] = vr + xre[idx];
                    out[S_DIM * B_DIM * E_DIM + idx] = vi + xim[idx];
                }
            }
        }
    }
}

// ---------------- K2: MFMA flash attention, S^T orientation, LDS-free K/V ----------------
// Round-6 rewrite [mechanism: Common-mistake #7 / m169 — K/V/Q for one (b,h)
// total <1.3 MB = L2-resident, so LDS staging is pure overhead]:
// Q, K and V fragments load DIRECTLY from global (L2) into registers in the
// exact MFMA frag pattern (lane base + immediate offsets). No K/V LDS tiles,
// no commit writes, no per-tile __syncthreads — waves are fully independent
// after launch. Only LDS use: per-wave P matrix (q->t redistribution for PV).
// Ps pitch 88 shorts (176B): rows stay 16B-aligned for the b128 read; the
// packed ushort4 P-write lands 2 lanes/bank-pair per 16-lane phase (2-way =
// free, m136) vs 4-way at pitch 80.
// T13 defer-max: skip the O-rescale when the running max doesn't grow by >8
// (p bounded by e^8, fine in fp32 accum; lrun stays exact).
// Scale 1/sqrt(128) is pre-folded into the q planes by cgemm<0>.
__global__ __launch_bounds__(256, 2) void attn_mfma(
    const unsigned short* __restrict__ qr, const unsigned short* __restrict__ qi,
    const unsigned short* __restrict__ kr, const unsigned short* __restrict__ ki,
    const unsigned short* __restrict__ vrt, const unsigned short* __restrict__ vit,
    unsigned short* __restrict__ updre, unsigned short* __restrict__ updim)
{
    __shared__ __align__(16) unsigned short Ps[4][16][88];   // per-wave P [q][t]

    const int tid  = threadIdx.x;
    const int wave = tid >> 6;
    const int lane = tid & 63;
    const int qt = (int)gridDim.x - 1 - blockIdx.x;  // long blocks launch first
    const int bh = blockIdx.y;
    const int q0 = qt * 64;
    const size_t base_qk = (size_t)bh * S_DIM * M_DIM;
    const size_t base_v  = (size_t)bh * V_DIM * S_DIM;

    const int fr = lane & 15;        // q col (QK/PV); A-frag row index
    const int fg = lane >> 4;        // quad 0..3
    const int fk = fg * 8;           // frag k offset (bf16)

    // ---- Q frags direct from global (per-wave distinct rows, loaded once) ----
    short8 Bqr[4], Bqi[4];
    {
        const size_t qo = base_qk + (size_t)(q0 + wave * 16 + fr) * M_DIM + fk;
        #pragma unroll
        for (int ks = 0; ks < 4; ++ks) {
            Bqr[ks] = *(const short8*)&qr[qo + ks * 32];
            Bqi[ks] = *(const short8*)&qi[qo + ks * 32];
        }
    }

    f32x4 Ore[4], Oim[4];   // O^T[v = vt*16+fg*4+reg][q = fr]
    #pragma unroll
    for (int vt = 0; vt < 4; ++vt) {
        Ore[vt] = (f32x4){0.f, 0.f, 0.f, 0.f};
        Oim[vt] = (f32x4){0.f, 0.f, 0.f, 0.f};
    }
    float mrun = -INFINITY, lrun = 0.f;
    const int qglob = q0 + wave * 16 + fr;      // this lane's q

    for (int t0 = 0; t0 <= q0; t0 += 64) {
        // ---- S^T = K Q^T (complex): K frags direct from L2 ----
        f32x4 Sre[4], Sim[4];   // t = tt*16 + fg*4 + reg, q = fr
        #pragma unroll
        for (int tt = 0; tt < 4; ++tt) {
            const size_t ko = base_qk + (size_t)(t0 + tt * 16 + fr) * M_DIM + fk;
            short8 Akr[4], Aki[4];
            #pragma unroll
            for (int ks = 0; ks < 4; ++ks) {
                Akr[ks] = *(const short8*)&kr[ko + ks * 32];
                Aki[ks] = *(const short8*)&ki[ko + ks * 32];
            }
            Sre[tt] = (f32x4){0.f, 0.f, 0.f, 0.f};
            Sim[tt] = (f32x4){0.f, 0.f, 0.f, 0.f};
            __builtin_amdgcn_s_setprio(1);
            #pragma unroll
            for (int ks = 0; ks < 4; ++ks) {
                int4v t = *(int4v*)&Aki[ks];
                t = t ^ (int)0x80008000;       // -Ki (transient)
                const short8 Akin = *(short8*)&t;
                Sre[tt] = __builtin_amdgcn_mfma_f32_16x16x32_bf16(Akr[ks], Bqr[ks], Sre[tt], 0, 0, 0);
                Sre[tt] = __builtin_amdgcn_mfma_f32_16x16x32_bf16(Akin,    Bqi[ks], Sre[tt], 0, 0, 0);
                Sim[tt] = __builtin_amdgcn_mfma_f32_16x16x32_bf16(Akr[ks], Bqi[ks], Sim[tt], 0, 0, 0);
                Sim[tt] = __builtin_amdgcn_mfma_f32_16x16x32_bf16(Aki[ks], Bqr[ks], Sim[tt], 0, 0, 0);
            }
            __builtin_amdgcn_s_setprio(0);
        }

        // ---- amplitude + causal mask (amp overwrites Sre); in-lane + 2 quad shfls ----
        float rowmax = -INFINITY;
        #pragma unroll
        for (int tt = 0; tt < 4; ++tt) {
            #pragma unroll
            for (int r = 0; r < 4; ++r) {
                const int tg = t0 + tt * 16 + fg * 4 + r;
                const float re = Sre[tt][r], im = Sim[tt][r];
                const float a = sqrtf(re * re + im * im);   // scale pre-folded into q
                const float av = (tg > qglob) ? -INFINITY : a;
                Sre[tt][r] = av;
                rowmax = fmaxf(rowmax, av);
            }
        }
        rowmax = fmaxf(rowmax, __shfl_xor(rowmax, 16));
        rowmax = fmaxf(rowmax, __shfl_xor(rowmax, 32));

        // T13 defer-max: rescale only when the max grows materially
        if (!__all(rowmax - mrun <= 8.0f)) {
            const float nm = fmaxf(mrun, rowmax);
            const float alpha = __expf(mrun - nm);
            mrun = nm;
            lrun *= alpha;
            #pragma unroll
            for (int vt = 0; vt < 4; ++vt)
                #pragma unroll
                for (int r = 0; r < 4; ++r) { Ore[vt][r] *= alpha; Oim[vt][r] *= alpha; }
        }

        float psum = 0.f;
        #pragma unroll
        for (int tt = 0; tt < 4; ++tt) {
            const float p0 = __expf(Sre[tt][0] - mrun);
            const float p1 = __expf(Sre[tt][1] - mrun);
            const float p2 = __expf(Sre[tt][2] - mrun);
            const float p3 = __expf(Sre[tt][3] - mrun);
            psum += p0 + p1 + p2 + p3;
            ushort4 pw;
            pw.x = f2bf(p0); pw.y = f2bf(p1); pw.z = f2bf(p2); pw.w = f2bf(p3);
            *(ushort4*)&Ps[wave][fr][tt * 16 + fg * 4] = pw;
        }
        psum += __shfl_xor(psum, 16);
        psum += __shfl_xor(psum, 32);
        lrun += psum;

        // ---- O^T += V^T P^T : V frags direct from L2, P frags from per-wave LDS ----
        const short8 Bp0 = *(const short8*)&Ps[wave][fr][fk];
        const short8 Bp1 = *(const short8*)&Ps[wave][fr][32 + fk];
        __builtin_amdgcn_s_setprio(1);
        #pragma unroll
        for (int vt = 0; vt < 4; ++vt) {
            const size_t vo = base_v + (size_t)(vt * 16 + fr) * S_DIM + t0 + fk;
            const short8 Ar0 = *(const short8*)&vrt[vo];
            const short8 Ar1 = *(const short8*)&vrt[vo + 32];
            const short8 Ai0 = *(const short8*)&vit[vo];
            const short8 Ai1 = *(const short8*)&vit[vo + 32];
            Ore[vt] = __builtin_amdgcn_mfma_f32_16x16x32_bf16(Ar0, Bp0, Ore[vt], 0, 0, 0);
            Ore[vt] = __builtin_amdgcn_mfma_f32_16x16x32_bf16(Ar1, Bp1, Ore[vt], 0, 0, 0);
            Oim[vt] = __builtin_amdgcn_mfma_f32_16x16x32_bf16(Ai0, Bp0, Oim[vt], 0, 0, 0);
            Oim[vt] = __builtin_amdgcn_mfma_f32_16x16x32_bf16(Ai1, Bp1, Oim[vt], 0, 0, 0);
        }
        __builtin_amdgcn_s_setprio(0);
    }

    // ---- epilogue: lane owns q = qglob; v = vt*16 + fg*4 + reg ----
    const int b = bh >> 4, h = bh & 15;
    const float inv = 1.0f / lrun;
    const size_t base = ((size_t)(qglob * B_DIM + b)) * E_DIM + h * V_DIM;
    #pragma unroll
    for (int vt = 0; vt < 4; ++vt) {
        ushort4 pr, pi;
        pr.x = f2bf(Ore[vt][0] * inv); pr.y = f2bf(Ore[vt][1] * inv);
        pr.z = f2bf(Ore[vt][2] * inv); pr.w = f2bf(Ore[vt][3] * inv);
        pi.x = f2bf(Oim[vt][0] * inv); pi.y = f2bf(Oim[vt][1] * inv);
        pi.z = f2bf(Oim[vt][2] * inv); pi.w = f2bf(Oim[vt][3] * inv);
        *(ushort4*)&updre[base + vt * 16 + fg * 4] = pr;
        *(ushort4*)&updim[base + vt * 16 + fg * 4] = pi;
    }
}

extern "C" void kernel_launch(void* const* d_in, const int* in_sizes, int n_in,
                              void* d_out, int out_size, void* d_ws, size_t ws_size,
                              hipStream_t stream) {
    const float* xre  = (const float*)d_in[0];
    const float* xim  = (const float*)d_in[1];
    const float* wqre = (const float*)d_in[2];
    const float* wqim = (const float*)d_in[3];
    const float* wkre = (const float*)d_in[4];
    const float* wkim = (const float*)d_in[5];
    const float* wvre = (const float*)d_in[6];
    const float* wvim = (const float*)d_in[7];
    const float* wore = (const float*)d_in[8];
    const float* woim = (const float*)d_in[9];
    float* out = (float*)d_out;

    // workspace layout (~160 MB)
    char* p = (char*)d_ws;
    const size_t QK = (size_t)B_DIM * H_DIM * S_DIM * M_DIM;   // 8.39M
    const size_t VS = (size_t)B_DIM * H_DIM * S_DIM * V_DIM;   // 4.19M
    const size_t SBE = (size_t)S_DIM * B_DIM * E_DIM;          // 4.19M
    unsigned short* qrw = (unsigned short*)p;  p += QK * 2;
    unsigned short* qiw = (unsigned short*)p;  p += QK * 2;
    unsigned short* krw = (unsigned short*)p;  p += QK * 2;
    unsigned short* kiw = (unsigned short*)p;  p += QK * 2;
    unsigned short* vrw = (unsigned short*)p;  p += VS * 2;
    unsigned short* viw = (unsigned short*)p;  p += VS * 2;
    unsigned short* vrt = (unsigned short*)p;  p += VS * 2;
    unsigned short* vit = (unsigned short*)p;  p += VS * 2;
    unsigned short* updre = (unsigned short*)p; p += SBE * 2;
    unsigned short* updim = (unsigned short*)p; p += SBE * 2;
    unsigned short* xbre  = (unsigned short*)p; p += SBE * 2;
    unsigned short* xbim  = (unsigned short*)p; p += SBE * 2;
    unsigned short* wbre  = (unsigned short*)p; p += (size_t)5120 * E_DIM * 2;
    unsigned short* wbim  = (unsigned short*)p; p += (size_t)5120 * E_DIM * 2;
    unsigned short* wtre  = (unsigned short*)p; p += (size_t)E_DIM * E_DIM * 2;
    unsigned short* wtim  = (unsigned short*)p; p += (size_t)E_DIM * E_DIM * 2;

    // bf16 conversion (single fused launch) + wo transpose
    convert_all<<<9216, 256, 0, stream>>>(xre, xim, wqre, wqim, wkre, wkim, wvre, wvim,
                                          xbre, xbim, wbre, wbim);
    transpose_wo<<<dim3(32, 32), 256, 0, stream>>>(wore, woim, wtre, wtim);

    // QKV projection (bf16 MFMA 16x16x32, 64x64 wave tile, T3-min dbuf)
    cgemm<0><<<dim3(32, 40), 256, 0, stream>>>(xbre, xbim, wbre, wbim,
                                               qrw, qiw, krw, kiw, vrw, viw,
                                               nullptr, nullptr, nullptr);
    // V -> V^T planes
    vtrans<<<dim3(16, 64), 256, 0, stream>>>(vrw, viw, vrt, vit);
    // MFMA flash attention (S^T orientation, LDS-free K/V)
    attn_mfma<<<dim3(16, 64), 256, 0, stream>>>(qrw, qiw, krw, kiw, vrt, vit, updre, updim);
    // output projection + residual (plain stores)
    cgemm<1><<<dim3(32, 8), 256, 0, stream>>>(updre, updim, wtre, wtim,
                                              nullptr, nullptr, nullptr, nullptr, nullptr, nullptr,
                                              xre, xim, out);
}

// Round 7
// 449.854 us; speedup vs baseline: 1.4980x; 1.4980x over previous
//
#include <hip/hip_runtime.h>
#include <math.h>

#define S_DIM 1024
#define B_DIM 4
#define E_DIM 1024
#define H_DIM 16
#define M_DIM 128
#define V_DIM 64

typedef __attribute__((ext_vector_type(8))) short short8;
typedef __attribute__((ext_vector_type(4))) float f32x4;
typedef __attribute__((ext_vector_type(4))) int int4v;

__device__ __forceinline__ unsigned short f2bf(float f) {
    union { float f; unsigned u; } v; v.f = f;
    unsigned r = v.u + 0x7FFFu + ((v.u >> 16) & 1u);   // round-to-nearest-even
    return (unsigned short)(r >> 16);
}

__device__ __forceinline__ void async16(const unsigned short* g, unsigned short* l) {
    __builtin_amdgcn_global_load_lds(
        (const __attribute__((address_space(1))) void*)g,
        (__attribute__((address_space(3))) void*)l,
        16, 0, 0);
}

// ---------------- convert: fp32 (re,im) -> bf16, all 4 tensors in one launch ----------------
// segments (in float4 units): x 1048576 | wq 524288 | wk 524288 | wv 262144
__global__ __launch_bounds__(256) void convert_all(
    const float* __restrict__ xre,  const float* __restrict__ xim,
    const float* __restrict__ wqre, const float* __restrict__ wqim,
    const float* __restrict__ wkre, const float* __restrict__ wkim,
    const float* __restrict__ wvre, const float* __restrict__ wvim,
    unsigned short* __restrict__ xbre, unsigned short* __restrict__ xbim,
    unsigned short* __restrict__ wbre, unsigned short* __restrict__ wbim)
{
    const int i = blockIdx.x * 256 + threadIdx.x;
    const float *re, *im;
    unsigned short *dr, *di;
    int j;
    if (i < 1048576)      { re = xre;  im = xim;  dr = xbre;               di = xbim;               j = i; }
    else if (i < 1572864) { re = wqre; im = wqim; dr = wbre;               di = wbim;               j = i - 1048576; }
    else if (i < 2097152) { re = wkre; im = wkim; dr = wbre + 2048 * 1024; di = wbim + 2048 * 1024; j = i - 1572864; }
    else                  { re = wvre; im = wvim; dr = wbre + 4096 * 1024; di = wbim + 4096 * 1024; j = i - 2097152; }
    float4 r = ((const float4*)re)[j];
    float4 m = ((const float4*)im)[j];
    ushort4 ro, mo;
    ro.x = f2bf(r.x); ro.y = f2bf(r.y); ro.z = f2bf(r.z); ro.w = f2bf(r.w);
    mo.x = f2bf(m.x); mo.y = f2bf(m.y); mo.z = f2bf(m.z); mo.w = f2bf(m.w);
    ((ushort4*)dr)[j] = ro;
    ((ushort4*)di)[j] = mo;
}

// wo (e,f) -> woT (f,e) bf16
__global__ __launch_bounds__(256) void transpose_wo(
    const float* __restrict__ wore, const float* __restrict__ woim,
    unsigned short* __restrict__ wtre, unsigned short* __restrict__ wtim)
{
    __shared__ float tr[32][33], ti[32][33];
    const int bx = blockIdx.x * 32;   // e range
    const int by = blockIdx.y * 32;   // f range
    const int tx = threadIdx.x & 31, ty = threadIdx.x >> 5;
    for (int i = ty; i < 32; i += 8) {
        tr[i][tx] = wore[(bx + i) * E_DIM + by + tx];
        ti[i][tx] = woim[(bx + i) * E_DIM + by + tx];
    }
    __syncthreads();
    for (int i = ty; i < 32; i += 8) {
        wtre[(by + i) * E_DIM + bx + tx] = f2bf(tr[tx][i]);
        wtim[(by + i) * E_DIM + bx + tx] = f2bf(ti[tx][i]);
    }
}

// v planes [bh][t][64] -> v^T planes [bh][v][1024]
__global__ __launch_bounds__(256) void vtrans(
    const unsigned short* __restrict__ vrp, const unsigned short* __restrict__ vip,
    unsigned short* __restrict__ vrt, unsigned short* __restrict__ vit)
{
    __shared__ unsigned short tl[2][64][66];
    const int tid = threadIdx.x;
    const int t0 = blockIdx.x * 64;
    const int bh = blockIdx.y;
    #pragma unroll
    for (int pl = 0; pl < 2; ++pl) {
        const unsigned short* src = pl ? vip : vrp;
        #pragma unroll
        for (int p = 0; p < 2; ++p) {
            const int row = p * 32 + (tid >> 3);
            const int col = (tid & 7) * 8;
            short8 d = *(const short8*)&src[((size_t)bh * S_DIM + t0 + row) * V_DIM + col];
            #pragma unroll
            for (int j = 0; j < 8; ++j) tl[pl][row][col + j] = (unsigned short)d[j];
        }
    }
    __syncthreads();
    #pragma unroll
    for (int pl = 0; pl < 2; ++pl) {
        unsigned short* dst = pl ? vit : vrt;
        #pragma unroll
        for (int p = 0; p < 2; ++p) {
            const int v = p * 32 + (tid >> 3);
            const int tc = (tid & 7) * 8;
            short8 d;
            #pragma unroll
            for (int j = 0; j < 8; ++j) d[j] = (short)tl[pl][tc + j][v];
            *(short8*)&dst[((size_t)bh * V_DIM + v) * S_DIM + t0 + tc] = d;
        }
    }
}

// ---------------- complex bf16 MFMA GEMM: C = A * B^T ----------------
// Frozen at round-5 state (154 us, MfmaUtil 51%, 0 bank conflicts):
// block 128x128, 4 waves (2x2), wave tile 64x64, 16x16x32 frags, BK=32,
// T3-min double-buffer, chunk-XOR swizzle. qscale (1/sqrt(128)) folded
// into the q-plane epilogue.
// MODE 0: Mr=4096 (s,b), Nc=5120 (q|k|v) -> bf16 planes qr/qi/kr/ki/vr/vi
// MODE 1: Mr=4096, Nc=1024 -> out = acc + x (fp32, stacked re/im), plain stores
template<int MODE>
__global__ __launch_bounds__(256, 2) void cgemm(
    const unsigned short* __restrict__ Are, const unsigned short* __restrict__ Aim,
    const unsigned short* __restrict__ Bre, const unsigned short* __restrict__ Bim,
    unsigned short* __restrict__ qrp, unsigned short* __restrict__ qip,
    unsigned short* __restrict__ krp, unsigned short* __restrict__ kip,
    unsigned short* __restrict__ vrp, unsigned short* __restrict__ vip,
    const float* __restrict__ xre, const float* __restrict__ xim,
    float* __restrict__ out)
{
    // 64 KB: 2 slice buffers x (Ar[128][32] | Ai[128][32] | Br[128][32] | Bi[128][32])
    __shared__ __align__(16) unsigned short lds[32768];
    const int tid  = threadIdx.x;
    const int wave = tid >> 6;
    const int lane = tid & 63;
    const int r0 = blockIdx.x * 128;
    const int j0 = blockIdx.y * 128;
    const int wm = (wave >> 1) * 64;   // m half
    const int wn = (wave & 1) * 64;    // n half

    f32x4 accre[4][4], accim[4][4];
    #pragma unroll
    for (int i = 0; i < 4; ++i)
        #pragma unroll
        for (int j = 0; j < 4; ++j) {
            accre[i][j] = (f32x4){0.f, 0.f, 0.f, 0.f};
            accim[i][j] = (f32x4){0.f, 0.f, 0.f, 0.f};
        }

    const int sr   = tid >> 2;
    const int sc   = (tid & 3) * 8;                          // physical chunk (shorts)
    const int scol = ((tid & 3) ^ ((tid >> 3) & 3)) * 8;     // pre-swizzled source col

    const int fr = lane & 15;                                // frag m/n index
    const int xc = ((lane >> 4) ^ ((lane >> 1) & 3)) * 8;    // swizzled k-chunk on read

    #define STAGE(sl, bb) { \
        const int kg = (sl) * 32; \
        unsigned short* b_ = &lds[(bb) * 16384]; \
        const size_t ga0 = (size_t)(r0 + sr) * E_DIM + kg + scol; \
        const size_t ga1 = (size_t)(r0 + 64 + sr) * E_DIM + kg + scol; \
        const size_t gb0 = (size_t)(j0 + sr) * E_DIM + kg + scol; \
        const size_t gb1 = (size_t)(j0 + 64 + sr) * E_DIM + kg + scol; \
        async16(Are + ga0, b_ + sr * 32 + sc); \
        async16(Are + ga1, b_ + (64 + sr) * 32 + sc); \
        async16(Aim + ga0, b_ + 4096 + sr * 32 + sc); \
        async16(Aim + ga1, b_ + 4096 + (64 + sr) * 32 + sc); \
        async16(Bre + gb0, b_ + 8192 + sr * 32 + sc); \
        async16(Bre + gb1, b_ + 8192 + (64 + sr) * 32 + sc); \
        async16(Bim + gb0, b_ + 12288 + sr * 32 + sc); \
        async16(Bim + gb1, b_ + 12288 + (64 + sr) * 32 + sc); }

    STAGE(0, 0)
    asm volatile("s_waitcnt vmcnt(0)" ::: "memory");
    __builtin_amdgcn_s_barrier();

    #pragma unroll 1
    for (int s = 0; s < 32; ++s) {
        if (s < 31) STAGE(s + 1, (s + 1) & 1)

        const unsigned short* buf = &lds[(s & 1) * 16384];
        short8 ar[4], ai[4];
        #pragma unroll
        for (int im = 0; im < 4; ++im) {
            const int ro = (wm + im * 16 + fr) * 32 + xc;
            ar[im] = *(const short8*)&buf[ro];
            ai[im] = *(const short8*)&buf[4096 + ro];
        }
        #pragma unroll
        for (int jn = 0; jn < 4; ++jn) {
            const int ro = (wn + jn * 16 + fr) * 32 + xc;
            const short8 br = *(const short8*)&buf[8192 + ro];
            const short8 bi = *(const short8*)&buf[12288 + ro];
            int4v t = *(int4v*)&bi;
            t = t ^ (int)0x80008000;       // bin = -bi (transient)
            const short8 bin = *(short8*)&t;
            #pragma unroll
            for (int im = 0; im < 4; ++im) {
                accre[im][jn] = __builtin_amdgcn_mfma_f32_16x16x32_bf16(ar[im], br,  accre[im][jn], 0, 0, 0);
                accre[im][jn] = __builtin_amdgcn_mfma_f32_16x16x32_bf16(ai[im], bin, accre[im][jn], 0, 0, 0);
                accim[im][jn] = __builtin_amdgcn_mfma_f32_16x16x32_bf16(ar[im], bi,  accim[im][jn], 0, 0, 0);
                accim[im][jn] = __builtin_amdgcn_mfma_f32_16x16x32_bf16(ai[im], br,  accim[im][jn], 0, 0, 0);
            }
        }

        if (s < 31) {
            asm volatile("s_waitcnt vmcnt(0)" ::: "memory");
            __builtin_amdgcn_s_barrier();
        }
    }
    #undef STAGE

    // epilogue: D row = (lane>>4)*4+reg, col = lane&15  [measured m89/m91]
    const float qscale = 0.088388347648318447f;  // 1/sqrt(128), folded into q planes
    #pragma unroll
    for (int im = 0; im < 4; ++im) {
        #pragma unroll
        for (int reg = 0; reg < 4; ++reg) {
            const int r = r0 + wm + im * 16 + (lane >> 4) * 4 + reg;
            #pragma unroll
            for (int jn = 0; jn < 4; ++jn) {
                const int j = j0 + wn + jn * 16 + fr;
                const float vr = accre[im][jn][reg];
                const float vi = accim[im][jn][reg];
                if (MODE == 0) {
                    const int s = r >> 2, b = r & 3;   // r = s*B + b
                    if (j < 2048) {
                        const int h = j >> 7, m = j & 127;
                        const size_t off = ((size_t)(b * H_DIM + h) * S_DIM + s) * M_DIM + m;
                        qrp[off] = f2bf(vr * qscale); qip[off] = f2bf(vi * qscale);
                    } else if (j < 4096) {
                        const int jl = j - 2048, h = jl >> 7, m = jl & 127;
                        const size_t off = ((size_t)(b * H_DIM + h) * S_DIM + s) * M_DIM + m;
                        krp[off] = f2bf(vr); kip[off] = f2bf(vi);
                    } else {
                        const int jl = j - 4096, h = jl >> 6, vv = jl & 63;
                        const size_t off = ((size_t)(b * H_DIM + h) * S_DIM + s) * V_DIM + vv;
                        vrp[off] = f2bf(vr); vip[off] = f2bf(vi);
                    }
                } else {
                    const int idx = r * E_DIM + j;
                    out[idx] = vr + xre[idx];
                    out[S_DIM * B_DIM * E_DIM + idx] = vi + xim[idx];
                }
            }
        }
    }
}

// ---------------- K2: MFMA flash attention, S^T orientation ----------------
// Round-7: REVERT to the staged-LDS structure (round-5) — round-6's direct-L2
// K/V loads quadrupled read traffic (4 waves x private tile loads) and the
// per-XCD 4 MB L2 thrashed under ~32 concurrent bh x 768 KB working sets ->
// FETCH 185 MB, HBM-bound at 360 us. Staging restores 1x per-block traffic.
// NEW: XCD-aware block remap (T1 mechanism): with dispatch n = bx + 16*by and
// the n%8->XCD heuristic, bh = (n&7) + 8*((n>>3)>>4), qt = 15-((n>>3)&15)
// (bijective over 1024). Each XCD serves 8 bh values, ~4 concurrently
// resident -> 3 MB <= 4 MB L2, so the 16x per-bh K/V re-read becomes L2 hits.
// Kept round-6 tweaks (all harness-verified): folded qscale, T13 defer-max,
// packed ushort4 Ps writes at pitch 88, setprio around MFMA clusters.
__global__ __launch_bounds__(256, 2) void attn_mfma(
    const unsigned short* __restrict__ qr, const unsigned short* __restrict__ qi,
    const unsigned short* __restrict__ kr, const unsigned short* __restrict__ ki,
    const unsigned short* __restrict__ vrt, const unsigned short* __restrict__ vit,
    unsigned short* __restrict__ updre, unsigned short* __restrict__ updim)
{
    __shared__ __align__(16) unsigned short Ks[2][64][136];  // K tile [plane][t][m] (Q staged here first)
    __shared__ __align__(16) unsigned short Vs[2][64][72];   // V^T tile [plane][v][t]
    __shared__ __align__(16) unsigned short Ps[4][16][88];   // per-wave P [q][t], pitch 88

    const int tid  = threadIdx.x;
    const int wave = tid >> 6;
    const int lane = tid & 63;

    // XCD-aware remap: n%8 ~ XCD; each XCD gets bh = {xcd, xcd+8, ..., xcd+56},
    // 16 consecutive blocks per bh (long qt dispatched first within each bh).
    const int n  = blockIdx.x + 16 * blockIdx.y;
    const int m_ = n >> 3;
    const int bh = (n & 7) + 8 * (m_ >> 4);
    const int qt = 15 - (m_ & 15);

    const int q0 = qt * 64;
    const size_t base_qk = (size_t)bh * S_DIM * M_DIM;
    const size_t base_v  = (size_t)bh * V_DIM * S_DIM;

    const int fr = lane & 15;        // q col (QK/PV); A-frag row index
    const int fg = lane >> 4;        // quad 0..3
    const int fk = fg * 8;           // frag k offset (bf16)

    // staging coords
    const int krow = tid >> 4, kcol = (tid & 15) * 8;   // K: 16 rows/pass
    const int vrow = tid >> 3, vcol = (tid & 7) * 8;    // V: 32 rows/pass

    // ---- stage Q tile into Ks, extract per-wave B-frags (Q[q=fr][m]) ----
    #pragma unroll
    for (int pl = 0; pl < 2; ++pl) {
        const unsigned short* src = pl ? qi : qr;
        #pragma unroll
        for (int p = 0; p < 4; ++p)
            *(short8*)&Ks[pl][p * 16 + krow][kcol] =
                *(const short8*)&src[base_qk + (size_t)(q0 + p * 16 + krow) * M_DIM + kcol];
    }
    __syncthreads();
    short8 Bqr[4], Bqi[4];
    {
        const int qrow = wave * 16 + fr;
        #pragma unroll
        for (int ks = 0; ks < 4; ++ks) {
            Bqr[ks] = *(const short8*)&Ks[0][qrow][ks * 32 + fk];
            Bqi[ks] = *(const short8*)&Ks[1][qrow][ks * 32 + fk];
        }
    }

    f32x4 Ore[4], Oim[4];   // O^T[v = vt*16+fg*4+reg][q = fr]
    #pragma unroll
    for (int vt = 0; vt < 4; ++vt) {
        Ore[vt] = (f32x4){0.f, 0.f, 0.f, 0.f};
        Oim[vt] = (f32x4){0.f, 0.f, 0.f, 0.f};
    }
    float mrun = -INFINITY, lrun = 0.f;
    const int qglob = q0 + wave * 16 + fr;      // this lane's q

    // ---- prefetch tile t0=0 into registers ----
    short8 pk[2][4], pv[2][2];
    #pragma unroll
    for (int pl = 0; pl < 2; ++pl) {
        const unsigned short* src = pl ? ki : kr;
        #pragma unroll
        for (int p = 0; p < 4; ++p)
            pk[pl][p] = *(const short8*)&src[base_qk + (size_t)(p * 16 + krow) * M_DIM + kcol];
    }
    #pragma unroll
    for (int pl = 0; pl < 2; ++pl) {
        const unsigned short* src = pl ? vit : vrt;
        #pragma unroll
        for (int p = 0; p < 2; ++p)
            pv[pl][p] = *(const short8*)&src[base_v + (size_t)(p * 32 + vrow) * S_DIM + vcol];
    }

    for (int t0 = 0; t0 <= q0; t0 += 64) {
        __syncthreads();   // prior readers of Ks/Vs done (iter0: Q frags extracted)
        // ---- commit prefetched K/V tile to LDS ----
        #pragma unroll
        for (int pl = 0; pl < 2; ++pl) {
            #pragma unroll
            for (int p = 0; p < 4; ++p)
                *(short8*)&Ks[pl][p * 16 + krow][kcol] = pk[pl][p];
            #pragma unroll
            for (int p = 0; p < 2; ++p)
                *(short8*)&Vs[pl][p * 32 + vrow][vcol] = pv[pl][p];
        }
        __syncthreads();

        // ---- issue next tile's global loads (consumed next iteration) ----
        if (t0 + 64 <= q0) {
            const int tn = t0 + 64;
            #pragma unroll
            for (int pl = 0; pl < 2; ++pl) {
                const unsigned short* src = pl ? ki : kr;
                #pragma unroll
                for (int p = 0; p < 4; ++p)
                    pk[pl][p] = *(const short8*)&src[base_qk + (size_t)(tn + p * 16 + krow) * M_DIM + kcol];
            }
            #pragma unroll
            for (int pl = 0; pl < 2; ++pl) {
                const unsigned short* src = pl ? vit : vrt;
                #pragma unroll
                for (int p = 0; p < 2; ++p)
                    pv[pl][p] = *(const short8*)&src[base_v + (size_t)(p * 32 + vrow) * S_DIM + tn + vcol];
            }
        }

        // ---- S^T = K Q^T (complex): A = K frags, B = Q frags ----
        f32x4 Sre[4], Sim[4];   // t = tt*16 + fg*4 + reg, q = fr
        __builtin_amdgcn_s_setprio(1);
        #pragma unroll
        for (int tt = 0; tt < 4; ++tt) {
            Sre[tt] = (f32x4){0.f, 0.f, 0.f, 0.f};
            Sim[tt] = (f32x4){0.f, 0.f, 0.f, 0.f};
            const int trow = tt * 16 + fr;
            #pragma unroll
            for (int ks = 0; ks < 4; ++ks) {
                const short8 Akr = *(const short8*)&Ks[0][trow][ks * 32 + fk];
                const short8 Aki = *(const short8*)&Ks[1][trow][ks * 32 + fk];
                int4v t = *(int4v*)&Aki;
                t = t ^ (int)0x80008000;       // -Ki (transient)
                const short8 Akin = *(short8*)&t;
                Sre[tt] = __builtin_amdgcn_mfma_f32_16x16x32_bf16(Akr,  Bqr[ks], Sre[tt], 0, 0, 0);
                Sre[tt] = __builtin_amdgcn_mfma_f32_16x16x32_bf16(Akin, Bqi[ks], Sre[tt], 0, 0, 0);
                Sim[tt] = __builtin_amdgcn_mfma_f32_16x16x32_bf16(Akr,  Bqi[ks], Sim[tt], 0, 0, 0);
                Sim[tt] = __builtin_amdgcn_mfma_f32_16x16x32_bf16(Aki,  Bqr[ks], Sim[tt], 0, 0, 0);
            }
        }
        __builtin_amdgcn_s_setprio(0);

        // ---- amplitude + causal mask (amp overwrites Sre); in-lane + 2 quad shfls ----
        float rowmax = -INFINITY;
        #pragma unroll
        for (int tt = 0; tt < 4; ++tt) {
            #pragma unroll
            for (int r = 0; r < 4; ++r) {
                const int tg = t0 + tt * 16 + fg * 4 + r;
                const float re = Sre[tt][r], im = Sim[tt][r];
                const float a = sqrtf(re * re + im * im);   // scale pre-folded into q
                const float av = (tg > qglob) ? -INFINITY : a;
                Sre[tt][r] = av;
                rowmax = fmaxf(rowmax, av);
            }
        }
        rowmax = fmaxf(rowmax, __shfl_xor(rowmax, 16));
        rowmax = fmaxf(rowmax, __shfl_xor(rowmax, 32));

        // T13 defer-max: rescale only when the max grows materially
        if (!__all(rowmax - mrun <= 8.0f)) {
            const float nm = fmaxf(mrun, rowmax);
            const float alpha = __expf(mrun - nm);
            mrun = nm;
            lrun *= alpha;
            #pragma unroll
            for (int vt = 0; vt < 4; ++vt)
                #pragma unroll
                for (int r = 0; r < 4; ++r) { Ore[vt][r] *= alpha; Oim[vt][r] *= alpha; }
        }

        float psum = 0.f;
        #pragma unroll
        for (int tt = 0; tt < 4; ++tt) {
            const float p0 = __expf(Sre[tt][0] - mrun);
            const float p1 = __expf(Sre[tt][1] - mrun);
            const float p2 = __expf(Sre[tt][2] - mrun);
            const float p3 = __expf(Sre[tt][3] - mrun);
            psum += p0 + p1 + p2 + p3;
            ushort4 pw;
            pw.x = f2bf(p0); pw.y = f2bf(p1); pw.z = f2bf(p2); pw.w = f2bf(p3);
            *(ushort4*)&Ps[wave][fr][tt * 16 + fg * 4] = pw;
        }
        psum += __shfl_xor(psum, 16);
        psum += __shfl_xor(psum, 32);
        lrun += psum;

        // ---- O^T += V^T P^T : A = V^T frags (LDS), B = P frags (per-wave LDS) ----
        const short8 Bp0 = *(const short8*)&Ps[wave][fr][fk];
        const short8 Bp1 = *(const short8*)&Ps[wave][fr][32 + fk];
        __builtin_amdgcn_s_setprio(1);
        #pragma unroll
        for (int vt = 0; vt < 4; ++vt) {
            const int vr2 = vt * 16 + fr;
            const short8 Ar0 = *(const short8*)&Vs[0][vr2][fk];
            const short8 Ar1 = *(const short8*)&Vs[0][vr2][32 + fk];
            const short8 Ai0 = *(const short8*)&Vs[1][vr2][fk];
            const short8 Ai1 = *(const short8*)&Vs[1][vr2][32 + fk];
            Ore[vt] = __builtin_amdgcn_mfma_f32_16x16x32_bf16(Ar0, Bp0, Ore[vt], 0, 0, 0);
            Ore[vt] = __builtin_amdgcn_mfma_f32_16x16x32_bf16(Ar1, Bp1, Ore[vt], 0, 0, 0);
            Oim[vt] = __builtin_amdgcn_mfma_f32_16x16x32_bf16(Ai0, Bp0, Oim[vt], 0, 0, 0);
            Oim[vt] = __builtin_amdgcn_mfma_f32_16x16x32_bf16(Ai1, Bp1, Oim[vt], 0, 0, 0);
        }
        __builtin_amdgcn_s_setprio(0);
    }

    // ---- epilogue: lane owns q = qglob; v = vt*16 + fg*4 + reg ----
    const int b = bh >> 4, h = bh & 15;
    const float inv = 1.0f / lrun;
    const size_t base = ((size_t)(qglob * B_DIM + b)) * E_DIM + h * V_DIM;
    #pragma unroll
    for (int vt = 0; vt < 4; ++vt) {
        ushort4 pr, pi;
        pr.x = f2bf(Ore[vt][0] * inv); pr.y = f2bf(Ore[vt][1] * inv);
        pr.z = f2bf(Ore[vt][2] * inv); pr.w = f2bf(Ore[vt][3] * inv);
        pi.x = f2bf(Oim[vt][0] * inv); pi.y = f2bf(Oim[vt][1] * inv);
        pi.z = f2bf(Oim[vt][2] * inv); pi.w = f2bf(Oim[vt][3] * inv);
        *(ushort4*)&updre[base + vt * 16 + fg * 4] = pr;
        *(ushort4*)&updim[base + vt * 16 + fg * 4] = pi;
    }
}

extern "C" void kernel_launch(void* const* d_in, const int* in_sizes, int n_in,
                              void* d_out, int out_size, void* d_ws, size_t ws_size,
                              hipStream_t stream) {
    const float* xre  = (const float*)d_in[0];
    const float* xim  = (const float*)d_in[1];
    const float* wqre = (const float*)d_in[2];
    const float* wqim = (const float*)d_in[3];
    const float* wkre = (const float*)d_in[4];
    const float* wkim = (const float*)d_in[5];
    const float* wvre = (const float*)d_in[6];
    const float* wvim = (const float*)d_in[7];
    const float* wore = (const float*)d_in[8];
    const float* woim = (const float*)d_in[9];
    float* out = (float*)d_out;

    // workspace layout (~160 MB)
    char* p = (char*)d_ws;
    const size_t QK = (size_t)B_DIM * H_DIM * S_DIM * M_DIM;   // 8.39M
    const size_t VS = (size_t)B_DIM * H_DIM * S_DIM * V_DIM;   // 4.19M
    const size_t SBE = (size_t)S_DIM * B_DIM * E_DIM;          // 4.19M
    unsigned short* qrw = (unsigned short*)p;  p += QK * 2;
    unsigned short* qiw = (unsigned short*)p;  p += QK * 2;
    unsigned short* krw = (unsigned short*)p;  p += QK * 2;
    unsigned short* kiw = (unsigned short*)p;  p += QK * 2;
    unsigned short* vrw = (unsigned short*)p;  p += VS * 2;
    unsigned short* viw = (unsigned short*)p;  p += VS * 2;
    unsigned short* vrt = (unsigned short*)p;  p += VS * 2;
    unsigned short* vit = (unsigned short*)p;  p += VS * 2;
    unsigned short* updre = (unsigned short*)p; p += SBE * 2;
    unsigned short* updim = (unsigned short*)p; p += SBE * 2;
    unsigned short* xbre  = (unsigned short*)p; p += SBE * 2;
    unsigned short* xbim  = (unsigned short*)p; p += SBE * 2;
    unsigned short* wbre  = (unsigned short*)p; p += (size_t)5120 * E_DIM * 2;
    unsigned short* wbim  = (unsigned short*)p; p += (size_t)5120 * E_DIM * 2;
    unsigned short* wtre  = (unsigned short*)p; p += (size_t)E_DIM * E_DIM * 2;
    unsigned short* wtim  = (unsigned short*)p; p += (size_t)E_DIM * E_DIM * 2;

    // bf16 conversion (single fused launch) + wo transpose
    convert_all<<<9216, 256, 0, stream>>>(xre, xim, wqre, wqim, wkre, wkim, wvre, wvim,
                                          xbre, xbim, wbre, wbim);
    transpose_wo<<<dim3(32, 32), 256, 0, stream>>>(wore, woim, wtre, wtim);

    // QKV projection (bf16 MFMA 16x16x32, 64x64 wave tile, T3-min dbuf)
    cgemm<0><<<dim3(32, 40), 256, 0, stream>>>(xbre, xbim, wbre, wbim,
                                               qrw, qiw, krw, kiw, vrw, viw,
                                               nullptr, nullptr, nullptr);
    // V -> V^T planes
    vtrans<<<dim3(16, 64), 256, 0, stream>>>(vrw, viw, vrt, vit);
    // MFMA flash attention (staged LDS + XCD-aware bh clustering)
    attn_mfma<<<dim3(16, 64), 256, 0, stream>>>(qrw, qiw, krw, kiw, vrt, vit, updre, updim);
    // output projection + residual (plain stores)
    cgemm<1><<<dim3(32, 8), 256, 0, stream>>>(updre, updim, wtre, wtim,
                                              nullptr, nullptr, nullptr, nullptr, nullptr, nullptr,
                                              xre, xim, out);
}